// Round 3
// baseline (259.566 us; speedup 1.0000x reference)
//
#include <hip/hip_runtime.h>
#include <math.h>

#define NNODES 200000
#define NG 1000
#define NPG 200
#define KNN 5
#define MD 128
#define S6 (1.0f / 6.0f)
#define HSTR 132        // fp32 h row stride (words): 132 % 32 = 4 -> rows spread across banks
#define HS_WORDS 26624  // max(200*132 = 26400 plain, 208*128 = 26624 packed frag reads)

typedef short short8 __attribute__((ext_vector_type(8)));
typedef float floatx4 __attribute__((ext_vector_type(4)));

// RNE bf16 split-pack: returns (bf16(v) << 16) | bf16(v - bf16(v))
__device__ __forceinline__ unsigned splitpack(float f) {
  unsigned u = __float_as_uint(f);
  unsigned hb = (u + 0x7fffu + ((u >> 16) & 1u)) >> 16;
  float hf = __uint_as_float(hb << 16);
  float r = f - hf;
  unsigned v = __float_as_uint(r);
  unsigned lb = (v + 0x7fffu + ((v >> 16) & 1u)) >> 16;
  return (hb << 16) | (lb & 0xffffu);
}

__device__ __forceinline__ void unpack8(int4 u, int4 v, short8* hi, short8* lo) {
  unsigned w[8] = {(unsigned)u.x, (unsigned)u.y, (unsigned)u.z, (unsigned)u.w,
                   (unsigned)v.x, (unsigned)v.y, (unsigned)v.z, (unsigned)v.w};
  short8 h, l;
#pragma unroll
  for (int i = 0; i < 8; i++) {
    h[i] = (short)(w[i] >> 16);
    l[i] = (short)(w[i] & 0xffffu);
  }
  *hi = h;
  *lo = l;
}

// gather-aggregate one float4 granule: relu(S6*(self + 5 neighbors) + b)
__device__ __forceinline__ float4 agg_row(const float* Hs, int r, int i1, int i2,
                                          int i3, int i4, int i5, int kq,
                                          const float* bb) {
  float4 s = *(const float4*)(Hs + r * HSTR + 4 * kq);
  float4 a1 = *(const float4*)(Hs + i1 * HSTR + 4 * kq);
  float4 a2 = *(const float4*)(Hs + i2 * HSTR + 4 * kq);
  float4 a3 = *(const float4*)(Hs + i3 * HSTR + 4 * kq);
  float4 a4 = *(const float4*)(Hs + i4 * HSTR + 4 * kq);
  float4 a5 = *(const float4*)(Hs + i5 * HSTR + 4 * kq);
  float4 bv = *(const float4*)(bb + 4 * kq);
  float4 o;
  o.x = fmaxf((((((s.x + a1.x) + a2.x) + a3.x) + a4.x) + a5.x) * S6 + bv.x, 0.0f);
  o.y = fmaxf((((((s.y + a1.y) + a2.y) + a3.y) + a4.y) + a5.y) * S6 + bv.y, 0.0f);
  o.z = fmaxf((((((s.z + a1.z) + a2.z) + a3.z) + a4.z) + a5.z) * S6 + bv.z, 0.0f);
  o.w = fmaxf((((((s.w + a1.w) + a2.w) + a3.w) + a4.w) + a5.w) * S6 + bv.w, 0.0f);
  return o;
}

// ---------------- kNN: one block per graph (validated) — LOCAL ids ----------------
__global__ __launch_bounds__(256) void knn_kernel(const float* __restrict__ pos,
                                                  int* __restrict__ knn) {
  __shared__ float sp[NPG * 3];
  int g = blockIdx.x;
  int t = threadIdx.x;
  for (int i = t; i < NPG * 3; i += 256) sp[i] = pos[(size_t)g * NPG * 3 + i];
  __syncthreads();
  if (t < NPG) {
    float x = sp[t * 3 + 0], y = sp[t * 3 + 1], z = sp[t * 3 + 2];
    float bd[KNN];
    int bi[KNN];
#pragma unroll
    for (int k = 0; k < KNN; k++) { bd[k] = 3.0e38f; bi[k] = 0; }
    for (int j = 0; j < NPG; j++) {
      if (j == t) continue;
      float dx = __fsub_rn(x, sp[j * 3 + 0]);
      float dy = __fsub_rn(y, sp[j * 3 + 1]);
      float dz = __fsub_rn(z, sp[j * 3 + 2]);
      float d2 = __fadd_rn(__fadd_rn(__fmul_rn(dx, dx), __fmul_rn(dy, dy)),
                           __fmul_rn(dz, dz));
      if (d2 < bd[KNN - 1]) {
        bd[KNN - 1] = d2; bi[KNN - 1] = j;
#pragma unroll
        for (int k = KNN - 1; k > 0; k--) {
          if (bd[k] < bd[k - 1]) {
            float td = bd[k]; bd[k] = bd[k - 1]; bd[k - 1] = td;
            int ti = bi[k]; bi[k] = bi[k - 1]; bi[k - 1] = ti;
          }
        }
      }
    }
#pragma unroll
    for (int k = 0; k < KNN; k++)
      knn[((size_t)g * NPG + t) * KNN + k] = bi[k];  // local id within graph
  }
}

// ---------------- embW0 = emb @ W0 (100x128 @ 128x128) ----------------
__global__ __launch_bounds__(256) void emb_gemm_kernel(const float* __restrict__ emb,
                                                       const float* __restrict__ W,
                                                       float* __restrict__ embW) {
  int idx = blockIdx.x * 256 + threadIdx.x;  // 12800 total
  int r = idx >> 7, c = idx & 127;
  float a = 0.0f;
  for (int k = 0; k < MD; k++) a += emb[r * MD + k] * W[k * MD + c];
  embW[idx] = a;
}

// ---------------- pre-pack W1,W2 into MFMA B-fragment layout (validated) ----------------
__global__ __launch_bounds__(256) void prepack_kernel(const float* __restrict__ convW,
                                                      unsigned short* __restrict__ WhiF,
                                                      unsigned short* __restrict__ WloF) {
  int idx = blockIdx.x * 256 + threadIdx.x;  // 0..4095
  int lane = idx & 63;
  int c = (idx >> 6) & 3;
  int T = (idx >> 8) & 7;
  int l = idx >> 11;  // 0..1 -> W1, W2
  const float* W = convW + (size_t)(l + 1) * MD * MD;
  int m = lane & 15, q = lane >> 4;
  int n = 16 * T + m;
  unsigned short hi[8], lo[8];
#pragma unroll
  for (int j = 0; j < 8; j++) {
    int k = 32 * c + 8 * q + j;
    unsigned p = splitpack(W[(size_t)k * MD + n]);
    hi[j] = (unsigned short)(p >> 16);
    lo[j] = (unsigned short)(p & 0xffffu);
  }
  *(short8*)(WhiF + (size_t)idx * 8) = *(short8*)hi;
  *(short8*)(WloF + (size_t)idx * 8) = *(short8*)lo;
}

// ---------------- fused per-graph megakernel ----------------
// One block = one graph, 1024 threads (16 waves), 1 block/CU (LDS-limited:
// 113 KB). amdgpu_waves_per_eu(4,4) pins allocator target to exactly 4
// waves/EU -> 128-VGPR budget. R2 lesson: __launch_bounds__(1024,4) only
// sets a MINIMUM of 4 waves/EU; allocator still targeted 8 (64 VGPR) and
// spilled ~65 MB of scratch to HBM (WRITE_SIZE evidence).
__global__ __launch_bounds__(1024)
__attribute__((amdgpu_waves_per_eu(4, 4))) void fused_kernel(
    const int* __restrict__ z, const int* __restrict__ knn,
    const float* __restrict__ embW, const float* __restrict__ convb,
    const unsigned short* __restrict__ WhiF, const unsigned short* __restrict__ WloF,
    const float* __restrict__ rW1, const float* __restrict__ rb1,
    const float* __restrict__ rW2, const float* __restrict__ rb2,
    const float* __restrict__ rW3, const float* __restrict__ rb3,
    float* __restrict__ out) {
  __shared__ float Hs[HS_WORDS];   // 106,496 B
  __shared__ int kl[NPG * KNN];    // 4,000 B
  __shared__ float red[8 * MD];    // 4,096 B
  __shared__ float pooled[MD];
  __shared__ float h1s[64];
  __shared__ float h2s[32];

  const int g = blockIdx.x;
  const int t = threadIdx.x;

  if (t < 250) ((int4*)kl)[t] = ((const int4*)(knn + (size_t)g * NPG * KNN))[t];

  const int r = t >> 2;    // row owned in agg/stage phases (active: r < 200)
  const int kq0 = t & 3;   // granule base

  // ---- stage h0 = embW[z] (plain fp32, stride 132) ----
  if (t < 4 * NPG) {
    int zi = z[g * NPG + r];
    const float4* E = (const float4*)(embW + (size_t)zi * MD);
#pragma unroll
    for (int p = 0; p < 8; p++) {
      int kq = kq0 + 4 * p;
      *(float4*)(Hs + r * HSTR + 4 * kq) = E[kq];
    }
  }
  __syncthreads();

  const int lane = t & 63;
  const int wv = t >> 6;
  const int m = lane & 15;
  const int q = lane >> 4;
  const int Tc = wv & 7;   // col-tile owned by this wave
  const int hg = wv >> 3;  // row-tile group: 0 -> tiles 0..6, 1 -> tiles 7..12
  const int nrt = hg ? 6 : 7;
  const int rt0 = hg ? 7 : 0;

#pragma unroll 1
  for (int l = 0; l < 2; l++) {
    // ---- aggregate + bias + relu + splitpack into regs ----
    unsigned pk[8][4];
    if (t < 4 * NPG) {
      const int* kn = kl + r * KNN;
      const int i1 = kn[0], i2 = kn[1], i3 = kn[2], i4 = kn[3], i5 = kn[4];
      const float* bb = convb + l * MD;
#pragma unroll
      for (int p = 0; p < 8; p++) {
        const int kq = kq0 + 4 * p;
        float4 o = agg_row(Hs, r, i1, i2, i3, i4, i5, kq, bb);
        pk[p][0] = splitpack(o.x);
        pk[p][1] = splitpack(o.y);
        pk[p][2] = splitpack(o.z);
        pk[p][3] = splitpack(o.w);
      }
    }
    __syncthreads();  // all h reads done before overwrite

    // ---- write packed x (stride 128, XOR-swizzled granules) ----
    if (t < 4 * NPG) {
      const int sw = r & 7;
      unsigned* Hu = (unsigned*)Hs;
#pragma unroll
      for (int p = 0; p < 8; p++) {
        const int kq = kq0 + 4 * p;
        int4 v;
        v.x = (int)pk[p][0]; v.y = (int)pk[p][1];
        v.z = (int)pk[p][2]; v.w = (int)pk[p][3];
        *(int4*)(Hu + r * MD + ((kq ^ sw) << 2)) = v;
      }
    }
    __syncthreads();

    // ---- MFMA: h_{l+1} = x @ W_{l+1} (split-bf16 3-product) ----
    const unsigned short* Wh = WhiF + (size_t)l * 16384;
    const unsigned short* Wl_ = WloF + (size_t)l * 16384;
    short8 bhi[4], blo[4];
#pragma unroll
    for (int c = 0; c < 4; c++) {
      const size_t off = ((size_t)(Tc * 4 + c) * 64 + lane) * 8;
      bhi[c] = *(const short8*)(Wh + off);
      blo[c] = *(const short8*)(Wl_ + off);
    }
    floatx4 acc[7];
#pragma unroll
    for (int i = 0; i < 7; i++) acc[i] = (floatx4){0.f, 0.f, 0.f, 0.f};
#pragma unroll
    for (int i = 0; i < 7; i++) {
      if (i < nrt) {
        const int ar = 16 * (rt0 + i) + m;  // rows 200..207 garbage: row-confined, discarded
        const unsigned* base = (const unsigned*)Hs + ar * MD;
        const int sw = m & 7;  // ar & 7 == m & 7 (16*RT multiple of 8)
#pragma unroll
        for (int c = 0; c < 4; c++) {
          const int g1 = (2 * q + 8 * c) ^ sw;
          const int g2 = (2 * q + 8 * c + 1) ^ sw;
          int4 u = *(const int4*)(base + (g1 << 2));
          int4 v = *(const int4*)(base + (g2 << 2));
          short8 ahi, alo;
          unpack8(u, v, &ahi, &alo);
          acc[i] = __builtin_amdgcn_mfma_f32_16x16x32_bf16(ahi, bhi[c], acc[i], 0, 0, 0);
          acc[i] = __builtin_amdgcn_mfma_f32_16x16x32_bf16(ahi, blo[c], acc[i], 0, 0, 0);
          acc[i] = __builtin_amdgcn_mfma_f32_16x16x32_bf16(alo, bhi[c], acc[i], 0, 0, 0);
        }
      }
    }
    __syncthreads();  // all packed-x frag reads done before overwrite

    // ---- write-back h_{l+1} (plain fp32, stride 132) ----
#pragma unroll
    for (int i = 0; i < 7; i++) {
      if (i < nrt) {
        const int col = 16 * Tc + m;  // C/D: col = lane&15, row = 4q + reg
#pragma unroll
        for (int reg = 0; reg < 4; reg++) {
          const int row = 16 * (rt0 + i) + 4 * q + reg;
          if (row < NPG) Hs[row * HSTR + col] = acc[i][reg];
        }
      }
    }
    __syncthreads();
  }

  // ---- tail: x3 = relu(S6*agg(h2) + b2) ----
  float4 xv[8];
  if (t < 4 * NPG) {
    const int* kn = kl + r * KNN;
    const int i1 = kn[0], i2 = kn[1], i3 = kn[2], i4 = kn[3], i5 = kn[4];
    const float* bb = convb + 2 * MD;
#pragma unroll
    for (int p = 0; p < 8; p++) {
      const int kq = kq0 + 4 * p;
      xv[p] = agg_row(Hs, r, i1, i2, i3, i4, i5, kq, bb);
    }
  }
  __syncthreads();
  if (t < 4 * NPG) {
#pragma unroll
    for (int p = 0; p < 8; p++) {
      const int kq = kq0 + 4 * p;
      *(float4*)(Hs + r * HSTR + 4 * kq) = xv[p];
    }
  }
  __syncthreads();

  // ---- mean pool: 8 row-groups x 128 cols ----
  {
    const int col = t & 127;
    const int j = t >> 7;  // 0..7, rows j*25..j*25+24
    float s = 0.f;
    for (int i = 0; i < 25; i++) s += Hs[(j * 25 + i) * HSTR + col];
    red[j * MD + col] = s;
  }
  __syncthreads();
  if (t < MD) {
    float p = 0.f;
#pragma unroll
    for (int j = 0; j < 8; j++) p += red[j * MD + t];
    pooled[t] = p * (1.0f / (float)NPG);
  }
  __syncthreads();

  // ---- regressor MLP ----
  if (t < 64) {
    float a = rb1[t];
    for (int c = 0; c < 128; c++) a += pooled[c] * rW1[c * 64 + t];
    h1s[t] = fmaxf(a, 0.0f);
  }
  __syncthreads();
  if (t < 32) {
    float a = rb2[t];
    for (int c = 0; c < 64; c++) a += h1s[c] * rW2[c * 32 + t];
    h2s[t] = fmaxf(a, 0.0f);
  }
  __syncthreads();
  if (t == 0) {
    float a = rb3[0];
    for (int c = 0; c < 32; c++) a += h2s[c] * rW3[c];
    out[g] = a;
  }
}

extern "C" void kernel_launch(void* const* d_in, const int* in_sizes, int n_in,
                              void* d_out, int out_size, void* d_ws, size_t ws_size,
                              hipStream_t stream) {
  const int* z = (const int*)d_in[0];
  const float* pos = (const float*)d_in[1];
  const float* emb = (const float*)d_in[3];
  const float* convW = (const float*)d_in[4];  // [3][128][128]
  const float* convb = (const float*)d_in[5];  // [3][128]
  const float* rW1 = (const float*)d_in[6];
  const float* rb1 = (const float*)d_in[7];
  const float* rW2 = (const float*)d_in[8];
  const float* rb2 = (const float*)d_in[9];
  const float* rW3 = (const float*)d_in[10];
  const float* rb3 = (const float*)d_in[11];
  float* out = (float*)d_out;

  char* ws = (char*)d_ws;
  int* knn = (int*)ws;                                      // 4,000,000 B
  float* embW = (float*)(ws + 4000000);                     // 51,200 B
  unsigned short* WhiF = (unsigned short*)(ws + 4051200);   // 65,536 B
  unsigned short* WloF = WhiF + 32768;                      // 65,536 B

  knn_kernel<<<NG, 256, 0, stream>>>(pos, knn);
  emb_gemm_kernel<<<50, 256, 0, stream>>>(emb, convW, embW);
  prepack_kernel<<<16, 256, 0, stream>>>(convW, WhiF, WloF);
  fused_kernel<<<NG, 1024, 0, stream>>>(z, knn, embW, convb, WhiF, WloF,
                                        rW1, rb1, rW2, rb2, rW3, rb3, out);
}

// Round 4
// 247.089 us; speedup vs baseline: 1.0505x; 1.0505x over previous
//
#include <hip/hip_runtime.h>
#include <math.h>

#define NNODES 200000
#define NG 1000
#define NPG 200
#define KNN 5
#define MD 128
#define S6 (1.0f / 6.0f)
#define HS_WORDS 26624  // 208 rows x 128 words, unified swizzled addressing

typedef short short8 __attribute__((ext_vector_type(8)));
typedef float floatx4 __attribute__((ext_vector_type(4)));

// RNE bf16 split-pack: returns (bf16(v) << 16) | bf16(v - bf16(v))
__device__ __forceinline__ unsigned splitpack(float f) {
  unsigned u = __float_as_uint(f);
  unsigned hb = (u + 0x7fffu + ((u >> 16) & 1u)) >> 16;
  float hf = __uint_as_float(hb << 16);
  float r = f - hf;
  unsigned v = __float_as_uint(r);
  unsigned lb = (v + 0x7fffu + ((v >> 16) & 1u)) >> 16;
  return (hb << 16) | (lb & 0xffffu);
}

__device__ __forceinline__ void unpack8(int4 u, int4 v, short8* hi, short8* lo) {
  unsigned w[8] = {(unsigned)u.x, (unsigned)u.y, (unsigned)u.z, (unsigned)u.w,
                   (unsigned)v.x, (unsigned)v.y, (unsigned)v.z, (unsigned)v.w};
  short8 h, l;
#pragma unroll
  for (int i = 0; i < 8; i++) {
    h[i] = (short)(w[i] >> 16);
    l[i] = (short)(w[i] & 0xffffu);
  }
  *hi = h;
  *lo = l;
}

// Unified swizzled addressing: value (row, col) lives at word
//   row*128 + (((col>>2) ^ (row&7)) << 2) + (col&3)
// Same mapping for fp32 h and packed split-bf16 x -> in-place column-group
// conversion is possible (agg is column-local).
__device__ __forceinline__ float4 rd4(const float* Hs, int row, int kq) {
  return *(const float4*)(Hs + row * MD + ((kq ^ (row & 7)) << 2));
}

// ---------------- kNN: one block per graph (validated) — LOCAL ids ----------------
__global__ __launch_bounds__(256) void knn_kernel(const float* __restrict__ pos,
                                                  int* __restrict__ knn) {
  __shared__ float sp[NPG * 3];
  int g = blockIdx.x;
  int t = threadIdx.x;
  for (int i = t; i < NPG * 3; i += 256) sp[i] = pos[(size_t)g * NPG * 3 + i];
  __syncthreads();
  if (t < NPG) {
    float x = sp[t * 3 + 0], y = sp[t * 3 + 1], z = sp[t * 3 + 2];
    float bd[KNN];
    int bi[KNN];
#pragma unroll
    for (int k = 0; k < KNN; k++) { bd[k] = 3.0e38f; bi[k] = 0; }
    for (int j = 0; j < NPG; j++) {
      if (j == t) continue;
      float dx = __fsub_rn(x, sp[j * 3 + 0]);
      float dy = __fsub_rn(y, sp[j * 3 + 1]);
      float dz = __fsub_rn(z, sp[j * 3 + 2]);
      float d2 = __fadd_rn(__fadd_rn(__fmul_rn(dx, dx), __fmul_rn(dy, dy)),
                           __fmul_rn(dz, dz));
      if (d2 < bd[KNN - 1]) {
        bd[KNN - 1] = d2; bi[KNN - 1] = j;
#pragma unroll
        for (int k = KNN - 1; k > 0; k--) {
          if (bd[k] < bd[k - 1]) {
            float td = bd[k]; bd[k] = bd[k - 1]; bd[k - 1] = td;
            int ti = bi[k]; bi[k] = bi[k - 1]; bi[k - 1] = ti;
          }
        }
      }
    }
#pragma unroll
    for (int k = 0; k < KNN; k++)
      knn[((size_t)g * NPG + t) * KNN + k] = bi[k];  // local id within graph
  }
}

// ---------------- embW0 = emb @ W0 (100x128 @ 128x128) ----------------
__global__ __launch_bounds__(256) void emb_gemm_kernel(const float* __restrict__ emb,
                                                       const float* __restrict__ W,
                                                       float* __restrict__ embW) {
  int idx = blockIdx.x * 256 + threadIdx.x;  // 12800 total
  int r = idx >> 7, c = idx & 127;
  float a = 0.0f;
  for (int k = 0; k < MD; k++) a += emb[r * MD + k] * W[k * MD + c];
  embW[idx] = a;
}

// ---------------- pre-pack W1,W2 into MFMA B-fragment layout (validated) ----------------
__global__ __launch_bounds__(256) void prepack_kernel(const float* __restrict__ convW,
                                                      unsigned short* __restrict__ WhiF,
                                                      unsigned short* __restrict__ WloF) {
  int idx = blockIdx.x * 256 + threadIdx.x;  // 0..4095
  int lane = idx & 63;
  int c = (idx >> 6) & 3;
  int T = (idx >> 8) & 7;
  int l = idx >> 11;  // 0..1 -> W1, W2
  const float* W = convW + (size_t)(l + 1) * MD * MD;
  int m = lane & 15, q = lane >> 4;
  int n = 16 * T + m;
  unsigned short hi[8], lo[8];
#pragma unroll
  for (int j = 0; j < 8; j++) {
    int k = 32 * c + 8 * q + j;
    unsigned p = splitpack(W[(size_t)k * MD + n]);
    hi[j] = (unsigned short)(p >> 16);
    lo[j] = (unsigned short)(p & 0xffffu);
  }
  *(short8*)(WhiF + (size_t)idx * 8) = *(short8*)hi;
  *(short8*)(WloF + (size_t)idx * 8) = *(short8*)lo;
}

// ---------------- fused per-graph megakernel ----------------
// One block = one graph, 1024 threads (16 waves), 1 block/CU (LDS-limited).
// R2/R3 lesson: allocator pins 64 VGPR regardless of launch_bounds /
// waves_per_eu hints -> design for 64: no register array lives across more
// than one barrier. Agg+pack is done IN PLACE column-group-wise (unified
// swizzled addressing for both fp32 h and packed x); MFMA loads B per
// k-chunk (c-outer loop).
__global__ __launch_bounds__(1024)
__attribute__((amdgpu_waves_per_eu(4, 4))) void fused_kernel(
    const int* __restrict__ z, const int* __restrict__ knn,
    const float* __restrict__ embW, const float* __restrict__ convb,
    const unsigned short* __restrict__ WhiF, const unsigned short* __restrict__ WloF,
    const float* __restrict__ rW1, const float* __restrict__ rb1,
    const float* __restrict__ rW2, const float* __restrict__ rb2,
    const float* __restrict__ rW3, const float* __restrict__ rb3,
    float* __restrict__ out) {
  __shared__ float Hs[HS_WORDS];   // 106,496 B
  __shared__ int kl[NPG * KNN];    // 4,000 B
  __shared__ float red[8 * MD];    // 4,096 B
  __shared__ float pooled[MD];
  __shared__ float h1s[64];
  __shared__ float h2s[32];

  const int g = blockIdx.x;
  const int t = threadIdx.x;

  if (t < 250) ((int4*)kl)[t] = ((const int4*)(knn + (size_t)g * NPG * KNN))[t];

  const int r = t >> 2;    // row owned in agg phases (active: r < 200)
  const int kq0 = t & 3;   // granule base

  // ---- stage h0 = embW[z] (fp32, unified addressing) ----
  if (t < 4 * NPG) {
    const int zi = z[g * NPG + r];
    const float4* E = (const float4*)(embW + (size_t)zi * MD);
    const int swr = r & 7;
#pragma unroll
    for (int p = 0; p < 8; p++) {
      const int kq = kq0 + 4 * p;
      *(float4*)(Hs + r * MD + ((kq ^ swr) << 2)) = E[kq];
    }
  }
  __syncthreads();

  const int lane = t & 63;
  const int wv = t >> 6;
  const int m = lane & 15;
  const int q = lane >> 4;
  const int Tc = wv & 7;   // col-tile owned by this wave
  const int hg = wv >> 3;  // row-tile group: 0 -> tiles 0..6, 1 -> tiles 7..12
  const int nrt = hg ? 6 : 7;
  const int rt0 = hg ? 7 : 0;

#pragma unroll 1
  for (int l = 0; l < 2; l++) {
    // ---- agg + bias + relu + pack, IN PLACE, two column groups ----
    const float* bb = convb + l * MD;
    int i1 = 0, i2 = 0, i3 = 0, i4 = 0, i5 = 0;
    if (t < 4 * NPG) {
      const int* kn = kl + r * KNN;
      i1 = kn[0]; i2 = kn[1]; i3 = kn[2]; i4 = kn[3]; i5 = kn[4];
    }
#pragma unroll 1
    for (int qg = 0; qg < 2; qg++) {
      unsigned pk[4][4];  // 16 regs, live only across ONE barrier
      if (t < 4 * NPG) {
#pragma unroll
        for (int p4 = 0; p4 < 4; p4++) {
          const int kq = kq0 + 16 * qg + 4 * p4;  // group qg: granules 16qg..16qg+15
          float4 s = rd4(Hs, r, kq);
          float4 a1 = rd4(Hs, i1, kq); s.x += a1.x; s.y += a1.y; s.z += a1.z; s.w += a1.w;
          float4 a2 = rd4(Hs, i2, kq); s.x += a2.x; s.y += a2.y; s.z += a2.z; s.w += a2.w;
          float4 a3 = rd4(Hs, i3, kq); s.x += a3.x; s.y += a3.y; s.z += a3.z; s.w += a3.w;
          float4 a4 = rd4(Hs, i4, kq); s.x += a4.x; s.y += a4.y; s.z += a4.z; s.w += a4.w;
          float4 a5 = rd4(Hs, i5, kq); s.x += a5.x; s.y += a5.y; s.z += a5.z; s.w += a5.w;
          const float4 bv = ((const float4*)bb)[kq];
          pk[p4][0] = splitpack(fmaxf(s.x * S6 + bv.x, 0.0f));
          pk[p4][1] = splitpack(fmaxf(s.y * S6 + bv.y, 0.0f));
          pk[p4][2] = splitpack(fmaxf(s.z * S6 + bv.z, 0.0f));
          pk[p4][3] = splitpack(fmaxf(s.w * S6 + bv.w, 0.0f));
        }
      }
      __syncthreads();  // group's fp32 reads complete
      if (t < 4 * NPG) {
        const int swr = r & 7;
        unsigned* Hu = (unsigned*)Hs;
#pragma unroll
        for (int p4 = 0; p4 < 4; p4++) {
          const int kq = kq0 + 16 * qg + 4 * p4;
          int4 w4;
          w4.x = (int)pk[p4][0]; w4.y = (int)pk[p4][1];
          w4.z = (int)pk[p4][2]; w4.w = (int)pk[p4][3];
          *(int4*)(Hu + r * MD + ((kq ^ swr) << 2)) = w4;
        }
      }
      __syncthreads();  // packed writes visible
    }

    // ---- MFMA: h_{l+1} = x @ W_{l+1} (split-bf16 3-product, c-outer) ----
    const unsigned short* Wh = WhiF + (size_t)l * 16384;
    const unsigned short* Wl_ = WloF + (size_t)l * 16384;
    floatx4 acc[7];
#pragma unroll
    for (int i = 0; i < 7; i++) acc[i] = (floatx4){0.f, 0.f, 0.f, 0.f};
    const int swm = m & 7;  // ar&7 == m&7 (16*RT multiple of 8)
#pragma unroll
    for (int c = 0; c < 4; c++) {
      const size_t off = ((size_t)(Tc * 4 + c) * 64 + lane) * 8;
      short8 bhi = *(const short8*)(Wh + off);
      short8 blo = *(const short8*)(Wl_ + off);
      const int g1 = (2 * q + 8 * c) ^ swm;
      const int g2 = (2 * q + 8 * c + 1) ^ swm;
#pragma unroll
      for (int i = 0; i < 7; i++) {
        if (i < nrt) {
          // rows 200..207 read garbage: row-confined in MFMA, discarded
          const unsigned* base = (const unsigned*)Hs + (16 * (rt0 + i) + m) * MD;
          int4 u = *(const int4*)(base + (g1 << 2));
          int4 v = *(const int4*)(base + (g2 << 2));
          short8 ahi, alo;
          unpack8(u, v, &ahi, &alo);
          acc[i] = __builtin_amdgcn_mfma_f32_16x16x32_bf16(ahi, bhi, acc[i], 0, 0, 0);
          acc[i] = __builtin_amdgcn_mfma_f32_16x16x32_bf16(ahi, blo, acc[i], 0, 0, 0);
          acc[i] = __builtin_amdgcn_mfma_f32_16x16x32_bf16(alo, bhi, acc[i], 0, 0, 0);
        }
      }
    }
    __syncthreads();  // all packed-x frag reads done before overwrite

    // ---- write-back h_{l+1} (fp32, unified addressing) ----
    {
      const int colg = 4 * Tc + (m >> 2);  // (16*Tc+m)>>2
      const int cw = m & 3;
#pragma unroll
      for (int i = 0; i < 7; i++) {
        if (i < nrt) {
#pragma unroll
          for (int reg = 0; reg < 4; reg++) {
            const int row = 16 * (rt0 + i) + 4 * q + reg;
            if (row < NPG)
              Hs[row * MD + ((colg ^ (row & 7)) << 2) + cw] = acc[i][reg];
          }
        }
      }
    }
    __syncthreads();
  }

  // ---- tail: x3 = relu(S6*agg(h2) + b2), in place, two column groups ----
  {
    const float* bb = convb + 2 * MD;
    int i1 = 0, i2 = 0, i3 = 0, i4 = 0, i5 = 0;
    if (t < 4 * NPG) {
      const int* kn = kl + r * KNN;
      i1 = kn[0]; i2 = kn[1]; i3 = kn[2]; i4 = kn[3]; i5 = kn[4];
    }
#pragma unroll 1
    for (int qg = 0; qg < 2; qg++) {
      float4 xv[4];
      if (t < 4 * NPG) {
#pragma unroll
        for (int p4 = 0; p4 < 4; p4++) {
          const int kq = kq0 + 16 * qg + 4 * p4;
          float4 s = rd4(Hs, r, kq);
          float4 a1 = rd4(Hs, i1, kq); s.x += a1.x; s.y += a1.y; s.z += a1.z; s.w += a1.w;
          float4 a2 = rd4(Hs, i2, kq); s.x += a2.x; s.y += a2.y; s.z += a2.z; s.w += a2.w;
          float4 a3 = rd4(Hs, i3, kq); s.x += a3.x; s.y += a3.y; s.z += a3.z; s.w += a3.w;
          float4 a4 = rd4(Hs, i4, kq); s.x += a4.x; s.y += a4.y; s.z += a4.z; s.w += a4.w;
          float4 a5 = rd4(Hs, i5, kq); s.x += a5.x; s.y += a5.y; s.z += a5.z; s.w += a5.w;
          const float4 bv = ((const float4*)bb)[kq];
          xv[p4].x = fmaxf(s.x * S6 + bv.x, 0.0f);
          xv[p4].y = fmaxf(s.y * S6 + bv.y, 0.0f);
          xv[p4].z = fmaxf(s.z * S6 + bv.z, 0.0f);
          xv[p4].w = fmaxf(s.w * S6 + bv.w, 0.0f);
        }
      }
      __syncthreads();
      if (t < 4 * NPG) {
        const int swr = r & 7;
#pragma unroll
        for (int p4 = 0; p4 < 4; p4++) {
          const int kq = kq0 + 16 * qg + 4 * p4;
          *(float4*)(Hs + r * MD + ((kq ^ swr) << 2)) = xv[p4];
        }
      }
      __syncthreads();
    }
  }

  // ---- mean pool: 8 row-groups x 128 cols (unified addressing reads) ----
  {
    const int col = t & 127;
    const int j = t >> 7;  // 0..7, rows j*25..j*25+24
    const int colg = col >> 2, cw = col & 3;
    float s = 0.f;
    for (int i = 0; i < 25; i++) {
      const int row = j * 25 + i;
      s += Hs[row * MD + ((colg ^ (row & 7)) << 2) + cw];
    }
    red[j * MD + col] = s;
  }
  __syncthreads();
  if (t < MD) {
    float p = 0.f;
#pragma unroll
    for (int j = 0; j < 8; j++) p += red[j * MD + t];
    pooled[t] = p * (1.0f / (float)NPG);
  }
  __syncthreads();

  // ---- regressor MLP ----
  if (t < 64) {
    float a = rb1[t];
    for (int c = 0; c < 128; c++) a += pooled[c] * rW1[c * 64 + t];
    h1s[t] = fmaxf(a, 0.0f);
  }
  __syncthreads();
  if (t < 32) {
    float a = rb2[t];
    for (int c = 0; c < 64; c++) a += h1s[c] * rW2[c * 32 + t];
    h2s[t] = fmaxf(a, 0.0f);
  }
  __syncthreads();
  if (t == 0) {
    float a = rb3[0];
    for (int c = 0; c < 32; c++) a += h2s[c] * rW3[c];
    out[g] = a;
  }
}

extern "C" void kernel_launch(void* const* d_in, const int* in_sizes, int n_in,
                              void* d_out, int out_size, void* d_ws, size_t ws_size,
                              hipStream_t stream) {
  const int* z = (const int*)d_in[0];
  const float* pos = (const float*)d_in[1];
  const float* emb = (const float*)d_in[3];
  const float* convW = (const float*)d_in[4];  // [3][128][128]
  const float* convb = (const float*)d_in[5];  // [3][128]
  const float* rW1 = (const float*)d_in[6];
  const float* rb1 = (const float*)d_in[7];
  const float* rW2 = (const float*)d_in[8];
  const float* rb2 = (const float*)d_in[9];
  const float* rW3 = (const float*)d_in[10];
  const float* rb3 = (const float*)d_in[11];
  float* out = (float*)d_out;

  char* ws = (char*)d_ws;
  int* knn = (int*)ws;                                      // 4,000,000 B
  float* embW = (float*)(ws + 4000000);                     // 51,200 B
  unsigned short* WhiF = (unsigned short*)(ws + 4051200);   // 65,536 B
  unsigned short* WloF = WhiF + 32768;                      // 65,536 B

  knn_kernel<<<NG, 256, 0, stream>>>(pos, knn);
  emb_gemm_kernel<<<50, 256, 0, stream>>>(emb, convW, embW);
  prepack_kernel<<<16, 256, 0, stream>>>(convW, WhiF, WloF);
  fused_kernel<<<NG, 1024, 0, stream>>>(z, knn, embW, convb, WhiF, WloF,
                                        rW1, rb1, rW2, rb2, rW3, rb3, out);
}